// Round 3
// baseline (204.297 us; speedup 1.0000x reference)
//
#include <hip/hip_runtime.h>

// Problem constants (T=512, B=16 -> 8192 tokens), all tensors float32
#define NTOK 8192
#define CDIM 512
#define NB   8
#define RD   64
#define OD   512
#define TPB_A 32           // tokens per phase-A block
#define XPAD 4             // pad x rows to 516 f32: conflict-free + float4-aligned
#define XROW (CDIM + XPAD)

typedef unsigned char u8;

// ---------------------------------------------------------------------------
// Phase A: 256 blocks x 256 threads, 32 tokens/block.
//  - stage x tile (32 x 512 f32) into LDS (padded rows)
//  - logits: one (token,bit) pair per thread, f64 accumulation (sign-critical)
//  - v = pw_w1 @ x: wave w handles tokens w*8..w*8+7, lane = w1 row
// ---------------------------------------------------------------------------
__global__ __launch_bounds__(256) void phaseA(
    const float* __restrict__ x, const float* __restrict__ map_w,
    const float* __restrict__ map_b, const float* __restrict__ w1,
    u8* __restrict__ q_out, float* __restrict__ v_out,
    float* __restrict__ loss_out)
{
    const int t    = threadIdx.x;
    const int tok0 = blockIdx.x * TPB_A;
    __shared__ float xs[TPB_A * XROW];   // ~66 KB

    // ---- stage x tile (coalesced float4 reads, padded LDS rows) ----
    const float4* xsrc = (const float4*)(x + (size_t)tok0 * CDIM);
    for (int i = t; i < TPB_A * (CDIM / 4); i += 256) {
        int r = i >> 7, c = i & 127;                    // CDIM/4 = 128
        *((float4*)(xs + r * XROW) + c) = xsrc[i];
    }
    __syncthreads();

    // ---- logits: thread t -> token (t>>3), bit (t&7), f64 accumulation ----
    {
        const int bit = t & 7, tk = t >> 3;             // tk in 0..31
        const float4* m4 = (const float4*)(map_w + (size_t)bit * CDIM);
        const float4* x4 = (const float4*)(xs + tk * XROW);
        double a0 = 0.0, a1 = 0.0;
        for (int j = 0; j < CDIM / 4; ++j) {
            float4 m = m4[j], xv = x4[j];
            a0 += (double)m.x * (double)xv.x + (double)m.y * (double)xv.y;
            a1 += (double)m.z * (double)xv.z + (double)m.w * (double)xv.w;
        }
        double k = a0 + a1 + (double)map_b[bit];
        unsigned long long m = __ballot(k > 0.0);
        const int lane = t & 63;
        if ((lane & 7) == 0) {
            int g = lane >> 3;                          // local token in wave
            q_out[tok0 + tk] = (u8)((m >> (g * 8)) & 0xFFull);
        }
    }

    // ---- v: wave w -> tokens w*8..w*8+7, lane r = w1 row ----
    {
        const int r  = t & 63;
        const int tg = t >> 6;                          // wave index 0..3
        const float4* w4 = (const float4*)(w1 + (size_t)r * CDIM);
        float acc[8] = {0.f,0.f,0.f,0.f,0.f,0.f,0.f,0.f};
        for (int j = 0; j < CDIM / 4; ++j) {
            float4 wv = w4[j];
            #pragma unroll
            for (int k = 0; k < 8; ++k) {
                float4 xv = *((const float4*)(xs + (tg * 8 + k) * XROW) + j);
                acc[k] += wv.x * xv.x + wv.y * xv.y + wv.z * xv.z + wv.w * xv.w;
            }
        }
        #pragma unroll
        for (int k = 0; k < 8; ++k)
            v_out[(size_t)(tok0 + tg * 8 + k) * RD + r] = acc[k];
    }

    if (blockIdx.x == 0 && t == 0) loss_out[0] = 0.0f;  // loss = 0
}

// ---------------------------------------------------------------------------
// Phase B: one block per code q (256 blocks x 512 threads). Build token list,
// thread t holds fused weights w21[q,t,:]+w22[255-q,t,:] (64 f32 regs),
// stream tokens through LDS in batches of 8.
// ---------------------------------------------------------------------------
__global__ __launch_bounds__(512) void phaseB(
    const u8* __restrict__ q_arr, const float* __restrict__ v_arr,
    const float* __restrict__ w21, const float* __restrict__ w22,
    const float* __restrict__ pwB, float* __restrict__ y)
{
    const int q = blockIdx.x;
    const int t = threadIdx.x;
    __shared__ unsigned short list[NTOK];   // 16 KB
    __shared__ int cnt;
    __shared__ float vs[8 * RD];            // 2 KB

    if (t == 0) cnt = 0;
    __syncthreads();
    for (int i = t; i < NTOK; i += 512)
        if ((int)q_arr[i] == q) list[atomicAdd(&cnt, 1)] = (unsigned short)i;
    __syncthreads();
    const int n = cnt;
    if (n == 0) return;

    // fused weight row for output o=t (contiguous 256 B per thread)
    const float4* pa = (const float4*)(w21 + (size_t)q * (OD * RD) + (size_t)t * RD);
    const float4* pb = (const float4*)(w22 + (size_t)(255 - q) * (OD * RD) + (size_t)t * RD);
    float w[RD];
    #pragma unroll
    for (int j = 0; j < RD / 4; ++j) {
        float4 a = pa[j], b = pb[j];
        w[j * 4 + 0] = a.x + b.x;
        w[j * 4 + 1] = a.y + b.y;
        w[j * 4 + 2] = a.z + b.z;
        w[j * 4 + 3] = a.w + b.w;
    }
    const float bias = pwB[t];

    for (int base = 0; base < n; base += 8) {
        const int nb = min(8, n - base);
        if (t < nb * RD)
            vs[t] = v_arr[(size_t)list[base + (t >> 6)] * RD + (t & 63)];
        __syncthreads();
        for (int i = 0; i < nb; ++i) {
            float acc = bias;
            #pragma unroll
            for (int r = 0; r < RD; ++r) acc += w[r] * vs[i * RD + r];
            y[(size_t)list[base + i] * OD + t] = acc;
        }
        __syncthreads();
    }
}

// ---------------------------------------------------------------------------
// Fallback (ws too small): workspace-free, one block per token.
// ---------------------------------------------------------------------------
__global__ __launch_bounds__(256) void mono(
    const float* __restrict__ x, const float* __restrict__ map_w,
    const float* __restrict__ map_b, const float* __restrict__ w1,
    const float* __restrict__ w21, const float* __restrict__ w22,
    const float* __restrict__ pwB, float* __restrict__ y)
{
    const int tok = blockIdx.x;
    const int t   = threadIdx.x;
    __shared__ float xsh[CDIM];
    __shared__ float vsh[RD];
    __shared__ int qsh;

    if (t == 0) qsh = 0;
    for (int i = t; i < CDIM; i += 256) xsh[i] = x[(size_t)tok * CDIM + i];
    __syncthreads();

    if (t < NB) {
        double a = 0.0;
        const float* mrow = map_w + (size_t)t * CDIM;
        for (int j = 0; j < CDIM; ++j) a += (double)mrow[j] * (double)xsh[j];
        a += (double)map_b[t];
        if (a > 0.0) atomicOr(&qsh, 1 << t);
    }
    if (t < RD) {
        const float* wrow = w1 + (size_t)t * CDIM;
        float acc = 0.f;
        for (int j = 0; j < CDIM; ++j) acc += wrow[j] * xsh[j];
        vsh[t] = acc;
    }
    __syncthreads();

    const int q = qsh;
    for (int o = t; o < OD; o += 256) {
        const float* pa = w21 + (size_t)q * (OD * RD) + (size_t)o * RD;
        const float* pb = w22 + (size_t)(255 - q) * (OD * RD) + (size_t)o * RD;
        float acc = pwB[o];
        for (int r = 0; r < RD; ++r) acc += (pa[r] + pb[r]) * vsh[r];
        y[(size_t)tok * OD + o] = acc;
    }
    if (tok == 0 && t == 0) y[(size_t)NTOK * OD] = 0.0f;
}

extern "C" void kernel_launch(void* const* d_in, const int* in_sizes, int n_in,
                              void* d_out, int out_size, void* d_ws, size_t ws_size,
                              hipStream_t stream) {
    const float* x     = (const float*)d_in[0];
    // d_in[1] = key: unused by the forward pass
    const float* map_w = (const float*)d_in[2];
    const float* map_b = (const float*)d_in[3];
    const float* w1    = (const float*)d_in[4];
    const float* w21   = (const float*)d_in[5];
    const float* w22   = (const float*)d_in[6];
    const float* pwB   = (const float*)d_in[7];
    float* out = (float*)d_out;

    const size_t need = (size_t)NTOK + (size_t)NTOK * RD * sizeof(float); // 8KB + 2MB
    if (ws_size >= need) {
        u8*    q_ws = (u8*)d_ws;
        float* v_ws = (float*)((char*)d_ws + NTOK);
        phaseA<<<NTOK / TPB_A, 256, 0, stream>>>(x, map_w, map_b, w1, q_ws, v_ws,
                                                 out + (size_t)NTOK * OD);
        phaseB<<<256, 512, 0, stream>>>(q_ws, v_ws, w21, w22, pwB, out);
    } else {
        mono<<<NTOK, 256, 0, stream>>>(x, map_w, map_b, w1, w21, w22, pwB, out);
    }
}